// Round 1
// baseline (1189.951 us; speedup 1.0000x reference)
//
#include <hip/hip_runtime.h>
#include <hip/hip_bf16.h>

// Problem: GSC_kan_56152402428565
// Two grouped KAN convs (1x1 then 3x3, G=8) + BatchNorm(training stats).
// B=16, C_in=128, C_out=256, H=W=64, NUM_BASIS=8 (grid 5, cubic).
// Round 1: correctness-first fp32 baseline; heavy loop = s_load weights +
// v_fmac with LDS-staged per-element features (silu + 8 spline bases).

#define NB 8
#define NF 9            // f0 = silu (base branch), f1..8 = spline bases
#define CIN 128
#define COUT 256
#define GROUPS 8
#define HW 4096
#define BATCH 16

// ---- per-scalar KAN features: f[0]=silu(v), f[1..8]=cubic B-spline bases ----
__device__ __forceinline__ void kan_features(float v, float* __restrict__ f) {
    f[0] = v / (1.0f + __expf(-v));
    float b[11];
#pragma unroll
    for (int j = 0; j < 11; ++j) {
        float t0 = (float)(j - 3) * 0.4f - 1.0f;
        float t1 = (float)(j - 2) * 0.4f - 1.0f;
        b[j] = (v >= t0 && v < t1) ? 1.0f : 0.0f;
    }
#pragma unroll
    for (int p = 1; p <= 3; ++p) {
        float inv = 1.0f / (0.4f * (float)p);
#pragma unroll
        for (int j = 0; j + p < 11; ++j) {
            float tj  = (float)(j - 3) * 0.4f - 1.0f;
            float tjp = (float)(j + p - 2) * 0.4f - 1.0f; // t[j+p+1]
            float left  = (v - tj) * inv;
            float right = (tjp - v) * inv;
            b[j] = left * b[j] + right * b[j + 1];
        }
    }
#pragma unroll
    for (int j = 0; j < NB; ++j) f[1 + j] = b[j];
}

// ---- weight repack: wp1[g][c16][f9][co32], wp2[g][c32][f9][tap9][co32] ----
__global__ void __launch_bounds__(256) repack_kernel(
    const float* __restrict__ wb1, const float* __restrict__ ws1,
    const float* __restrict__ wb2, const float* __restrict__ ws2,
    float* __restrict__ wp1, float* __restrict__ wp2) {
    int i = blockIdx.x * 256 + threadIdx.x;
    if (i < 8 * 16 * 9 * 32) {
        int co = i & 31;
        int t = i >> 5;
        int f = t % 9; t /= 9;
        int c = t & 15; int g = t >> 4;
        int cog = g * 32 + co;
        wp1[i] = (f == 0) ? wb1[cog * 16 + c]
                          : ws1[cog * 128 + c * 8 + (f - 1)];
    }
    if (i < 8 * 32 * 9 * 9 * 32) {
        int co = i & 31;
        int t = i >> 5;
        int tap = t % 9; t /= 9;
        int f = t % 9; t /= 9;
        int c = t & 31; int g = t >> 5;
        int cog = g * 32 + co;
        wp2[i] = (f == 0) ? wb2[(cog * 32 + c) * 9 + tap]
                          : ws2[(cog * 256 + c * 8 + (f - 1)) * 9 + tap];
    }
}

// ---- layer 1: 1x1 grouped KAN conv. block: (b,g, 256-pos tile); thread: 1 pos x 32 co
__global__ void __launch_bounds__(256) kan1_kernel(
    const float* __restrict__ x, const float* __restrict__ wp1,
    const float* __restrict__ bb1, float* __restrict__ h1) {
    int tid = threadIdx.x;
    int blk = blockIdx.x;              // ((b*8)+g)*16 + t
    int t = blk & 15;
    int g = (blk >> 4) & 7;
    int b = blk >> 7;
    int pos = t * 256 + tid;

    float acc[32];
    const float* bb = bb1 + g * 32;
#pragma unroll
    for (int co = 0; co < 32; ++co) acc[co] = bb[co];

    for (int c = 0; c < 16; ++c) {
        float v = x[(b * CIN + g * 16 + c) * HW + pos];
        float ft[NF];
        kan_features(v, ft);
        const float* wp = wp1 + ((g * 16 + c) * 9) * 32;
        for (int f = 0; f < NF; ++f) {
            float fv = ft[f];
#pragma unroll
            for (int co = 0; co < 32; ++co)
                acc[co] = fmaf(wp[f * 32 + co], fv, acc[co]);
        }
    }
    float* op = h1 + (b * COUT + g * 32) * HW + pos;
#pragma unroll
    for (int co = 0; co < 32; ++co) op[co * HW] = acc[co];
}

// ---- layer 2: 3x3 grouped KAN conv, padding 1.
// block: (b,g, 16x16 tile); thread: 1 pos x 32 co; features LDS-staged 2 ch at a time.
__global__ void __launch_bounds__(256) kan2_kernel(
    const float* __restrict__ h1, const float* __restrict__ wp2,
    const float* __restrict__ bb2, float* __restrict__ h2) {
    __shared__ float feat[2 * NF * 324];   // [c2][f9][18*18]
    int tid = threadIdx.x;
    int blk = blockIdx.x;                  // ((b*8)+g)*16 + tile
    int tile = blk & 15;
    int g = (blk >> 4) & 7;
    int b = blk >> 7;
    int ty = (tile >> 2) * 16, tx = (tile & 3) * 16;
    int y0 = tid >> 4, x0 = tid & 15;

    float acc[32];
#pragma unroll
    for (int co = 0; co < 32; ++co) acc[co] = bb2[g * 32 + co];

    for (int cc = 0; cc < 16; ++cc) {      // 16 chunks x 2 channels
        __syncthreads();
        for (int e = tid; e < 648; e += 256) {
            int c = (e >= 324) ? 1 : 0;
            int p = e - c * 324;
            int iy = ty + p / 18 - 1;
            int ix = tx + (p % 18) - 1;
            float ft[NF];
            if ((unsigned)iy < 64u && (unsigned)ix < 64u) {
                float v = h1[((b * COUT + g * 32 + cc * 2 + c) * 64 + iy) * 64 + ix];
                kan_features(v, ft);
            } else {
#pragma unroll
                for (int f = 0; f < NF; ++f) ft[f] = 0.0f;  // zero-padded conv input
            }
#pragma unroll
            for (int f = 0; f < NF; ++f) feat[(c * NF + f) * 324 + p] = ft[f];
        }
        __syncthreads();
#pragma unroll
        for (int c = 0; c < 2; ++c) {
            const float* wbase = wp2 + ((g * 32 + cc * 2 + c) * 9) * 9 * 32;
            for (int f = 0; f < NF; ++f) {
                const float* frow = &feat[(c * NF + f) * 324];
                const float* wrow = wbase + f * 9 * 32;
#pragma unroll
                for (int ky = 0; ky < 3; ++ky) {
#pragma unroll
                    for (int kx = 0; kx < 3; ++kx) {
                        float fv = frow[(y0 + ky) * 18 + (x0 + kx)];
                        const float* wpt = wrow + (ky * 3 + kx) * 32;
#pragma unroll
                        for (int co = 0; co < 32; ++co)
                            acc[co] = fmaf(wpt[co], fv, acc[co]);
                    }
                }
            }
        }
    }
    float* op = h2 + ((b * COUT + g * 32) * 64 + (ty + y0)) * 64 + (tx + x0);
#pragma unroll
    for (int co = 0; co < 32; ++co) op[co * HW] = acc[co];
}

// ---- BN stats: one block per channel; writes scale/shift ----
__global__ void __launch_bounds__(256) bnstats_kernel(
    const float* __restrict__ h2, const float* __restrict__ gamma,
    const float* __restrict__ beta, float* __restrict__ stats) {
    int co = blockIdx.x;
    int tid = threadIdx.x;
    float s = 0.0f, ss = 0.0f;
    for (int b = 0; b < BATCH; ++b) {
        const float* p = h2 + (b * COUT + co) * HW;
        for (int i = tid; i < HW; i += 256) {
            float v = p[i];
            s += v;
            ss = fmaf(v, v, ss);
        }
    }
    __shared__ float r1[256], r2[256];
    r1[tid] = s; r2[tid] = ss;
    __syncthreads();
    for (int o = 128; o > 0; o >>= 1) {
        if (tid < o) { r1[tid] += r1[tid + o]; r2[tid] += r2[tid + o]; }
        __syncthreads();
    }
    if (tid == 0) {
        const float invn = 1.0f / 65536.0f;
        float mean = r1[0] * invn;
        float var = r2[0] * invn - mean * mean;
        float sc = gamma[co] * rsqrtf(var + 1e-5f);
        stats[2 * co] = sc;
        stats[2 * co + 1] = beta[co] - mean * sc;
    }
}

// ---- BN apply: out = h2*scale + shift (float4) ----
__global__ void __launch_bounds__(256) bnapply_kernel(
    const float* __restrict__ h2, const float* __restrict__ stats,
    float* __restrict__ out, int n4) {
    int i = blockIdx.x * 256 + threadIdx.x;
    if (i >= n4) return;
    int co = (i >> 10) & 255;          // 1024 float4 per (b,co) plane
    float sc = stats[2 * co], sh = stats[2 * co + 1];
    float4 v = reinterpret_cast<const float4*>(h2)[i];
    float4 o;
    o.x = fmaf(v.x, sc, sh);
    o.y = fmaf(v.y, sc, sh);
    o.z = fmaf(v.z, sc, sh);
    o.w = fmaf(v.w, sc, sh);
    reinterpret_cast<float4*>(out)[i] = o;
}

extern "C" void kernel_launch(void* const* d_in, const int* in_sizes, int n_in,
                              void* d_out, int out_size, void* d_ws, size_t ws_size,
                              hipStream_t stream) {
    const float* x   = (const float*)d_in[0];
    const float* wb1 = (const float*)d_in[1];
    const float* bb1 = (const float*)d_in[2];
    const float* ws1 = (const float*)d_in[3];
    const float* wb2 = (const float*)d_in[4];
    const float* bb2 = (const float*)d_in[5];
    const float* ws2 = (const float*)d_in[6];
    const float* gamma = (const float*)d_in[7];
    const float* beta  = (const float*)d_in[8];

    float* ws = (float*)d_ws;
    const size_t HSZ = (size_t)BATCH * COUT * HW;   // 16,777,216
    float* h1    = ws;
    float* h2    = h1 + HSZ;
    float* wp1   = h2 + HSZ;                        // 36,864
    float* wp2   = wp1 + 36864;                     // 663,552
    float* stats = wp2 + 663552;                    // 512

    repack_kernel<<<(663552 + 255) / 256, 256, 0, stream>>>(wb1, ws1, wb2, ws2, wp1, wp2);
    kan1_kernel<<<BATCH * GROUPS * 16, 256, 0, stream>>>(x, wp1, bb1, h1);
    kan2_kernel<<<BATCH * GROUPS * 16, 256, 0, stream>>>(h1, wp2, bb2, h2);
    bnstats_kernel<<<COUT, 256, 0, stream>>>(h2, gamma, beta, stats);
    bnapply_kernel<<<(4194304 + 255) / 256, 256, 0, stream>>>(h2, stats, (float*)d_out, 4194304);
}

// Round 4
// 340.005 us; speedup vs baseline: 3.4998x; 3.4998x over previous
//
#include <hip/hip_runtime.h>
#include <hip/hip_bf16.h>
#include <stdint.h>

// GSC_kan: two grouped KAN convs (1x1, 3x3; G=8) + BatchNorm.
// Round 4: resubmit of R3 (R3 failed on infra: UnresponsiveContainer).
// kan2 = bf16 MFMA implicit GEMM, 4-ch chunks, 41472B LDS, XOR-swizzled.

#define NB 8
#define NF 9
#define CIN 128
#define COUT 256
#define GROUPS 8
#define HW 4096
#define BATCH 16

#define WFS_ELEMS 589824   // 256 * 32 * 8 * 9
#define WFB_ELEMS 73728    // 256 * 32 * 9

typedef __attribute__((ext_vector_type(8))) short bf16x8;
typedef __attribute__((ext_vector_type(4))) float f32x4;

__device__ __forceinline__ unsigned bf16r(float f) {
    union { float f; unsigned u; } c; c.f = f;
    unsigned r = c.u + 0x7FFF + ((c.u >> 16) & 1);   // RNE
    return r >> 16;
}
__device__ __forceinline__ unsigned bfpack(float lo, float hi) {
    return bf16r(lo) | (bf16r(hi) << 16);
}

// uniform-knot cubic B-spline: 4 nonzero cardinal weights at interval k.
// knots t_j = -1 + (j-3)*0.4 (j=0..11); s=(v+2.2)*2.5; nonzero bases k-3..k.
__device__ __forceinline__ void spline_w(float v, float& w0, float& w1,
                                         float& w2, float& w3, int& k) {
    float s = (v + 2.2f) * 2.5f;
    float fk = floorf(s);
    k = (int)fk;
    float u = s - fk;
    float um = 1.0f - u;
    float u2 = u * u, u3 = u2 * u;
    w0 = um * um * um * (1.0f / 6.0f);
    w1 = (3.0f * u3 - 6.0f * u2 + 4.0f) * (1.0f / 6.0f);
    w2 = (-3.0f * u3 + 3.0f * u2 + 3.0f * u + 1.0f) * (1.0f / 6.0f);
    w3 = u3 * (1.0f / 6.0f);
}

__device__ __forceinline__ void kan_features_fast(float v, float* __restrict__ f) {
    f[0] = v / (1.0f + __expf(-v));
    float w0, w1, w2, w3; int k;
    spline_w(v, w0, w1, w2, w3, k);
#pragma unroll
    for (int idx = 0; idx < 8; ++idx) {
        int d = idx - k + 3;
        float r = (d == 0) ? w0 : 0.0f;
        r = (d == 1) ? w1 : r;
        r = (d == 2) ? w2 : r;
        r = (d == 3) ? w3 : r;
        f[1 + idx] = r;
    }
}

// ---- repack: wp1 fp32 [g][c16][f9][co32]; wfs/wfb bf16 B-fragment layouts ----
// wfs: [g8][cc8][dx3][dy3][nf2][lane64][j8]  (spline 3x3; c_loc=cc*4+(lane>>4), j=basis)
// wfb: [g8][dx3][dy3][nf2][lane64][j8]       (base 3x3; ch=(lane>>4)*8+j)
__global__ void __launch_bounds__(256) repack2_kernel(
    const float* __restrict__ wb1, const float* __restrict__ ws1,
    const float* __restrict__ wb2, const float* __restrict__ ws2,
    float* __restrict__ wp1, unsigned short* __restrict__ wfs,
    unsigned short* __restrict__ wfb) {
    int i = blockIdx.x * 256 + threadIdx.x;
    if (i < 8 * 16 * 9 * 32) {
        int co = i & 31;
        int t = i >> 5;
        int f = t % 9; t /= 9;
        int c = t & 15; int g = t >> 4;
        int cog = g * 32 + co;
        wp1[i] = (f == 0) ? wb1[cog * 16 + c]
                          : ws1[cog * 128 + c * 8 + (f - 1)];
    }
    if (i < WFB_ELEMS) {
        int j = i & 7;
        int lane = (i >> 3) & 63;
        int nf = (i >> 9) & 1;
        int t = i >> 10;
        int dy = t % 3; t /= 3;
        int dx = t % 3; t /= 3;
        int g = t;
        int ch = (lane >> 4) * 8 + j;
        int cog = g * 32 + nf * 16 + (lane & 15);
        wfb[i] = (unsigned short)bf16r(wb2[((cog * 32 + ch) * 3 + dy) * 3 + dx]);
    }
    if (i < WFS_ELEMS) {
        int j = i & 7;
        int t = i >> 3;
        int lane = t & 63; t >>= 6;
        int nf = t & 1; t >>= 1;
        int dy = t % 3; t /= 3;
        int dx = t % 3; t /= 3;
        int cc = t & 7; t >>= 3;
        int g = t;
        int c_loc = cc * 4 + (lane >> 4);
        int cog = g * 32 + nf * 16 + (lane & 15);
        float v = ws2[((cog * 256 + c_loc * 8 + j) * 3 + dy) * 3 + dx];
        wfs[i] = (unsigned short)bf16r(v);
    }
}

// ---- layer 1: 1x1 grouped KAN conv (fp32 VALU, fast basis eval) ----
__global__ void __launch_bounds__(256) kan1_kernel(
    const float* __restrict__ x, const float* __restrict__ wp1,
    const float* __restrict__ bb1, float* __restrict__ h1) {
    int tid = threadIdx.x;
    int blk = blockIdx.x;
    int t = blk & 15;
    int g = (blk >> 4) & 7;
    int b = blk >> 7;
    int pos = t * 256 + tid;

    float acc[32];
    const float* bb = bb1 + g * 32;
#pragma unroll
    for (int co = 0; co < 32; ++co) acc[co] = bb[co];

    for (int c = 0; c < 16; ++c) {
        float v = x[(b * CIN + g * 16 + c) * HW + pos];
        float ft[NF];
        kan_features_fast(v, ft);
        const float* wp = wp1 + ((g * 16 + c) * 9) * 32;
        for (int f = 0; f < NF; ++f) {
            float fv = ft[f];
#pragma unroll
            for (int co = 0; co < 32; ++co)
                acc[co] = fmaf(wp[f * 32 + co], fv, acc[co]);
        }
    }
    float* op = h1 + (b * COUT + g * 32) * HW + pos;
#pragma unroll
    for (int co = 0; co < 32; ++co) op[co * HW] = acc[co];
}

// ---- layer 2: 3x3 grouped KAN conv via bf16 MFMA implicit GEMM ----
// block: (b,g,16x16 tile), 4 waves; wave -> 4 output rows x 32 co.
// LDS: spl[324 pos][4ch x 8basis = 64B], slu[324 pos][32ch x 2B = 64B],
// both XOR-swizzled at 16B granule: chunk' = chunk ^ ((p>>1)&3).
__global__ void __launch_bounds__(256) kan2_mfma_kernel(
    const float* __restrict__ h1, const bf16x8* __restrict__ wfs,
    const bf16x8* __restrict__ wfb, const float* __restrict__ bb2,
    float* __restrict__ h2) {
    __shared__ __align__(16) unsigned char lds[41472];
    unsigned char* spl = lds;            // 20736 B
    unsigned char* slu = lds + 20736;    // 20736 B

    const int tid = threadIdx.x;
    const int lane = tid & 63;
    const int w = tid >> 6;
    const int blk = blockIdx.x;
    const int tile = blk & 15;
    const int g = (blk >> 4) & 7;
    const int b = blk >> 7;
    const int ty = (tile >> 2) * 16, tx = (tile & 3) * 16;
    const int lrow = lane & 15;   // A-row (x pos) & B-col (co)
    const int lhi = lane >> 4;    // k-block; D-row block

    f32x4 acc[4][2];
#pragma unroll
    for (int y = 0; y < 4; ++y)
#pragma unroll
        for (int nf = 0; nf < 2; ++nf) {
            float bias = bb2[g * 32 + nf * 16 + lrow];
            acc[y][nf] = (f32x4){bias, bias, bias, bias};
        }

    const float* h1g = h1 + (size_t)(b * COUT + g * 32) * HW;
    const int hybase = w * 4;

    for (int cc = 0; cc < 8; ++cc) {
        __syncthreads();
        // stage 4 channels x 324 halo positions
        for (int e = tid; e < 1296; e += 256) {
            int ch = e / 324;                  // 0..3
            int p = e - ch * 324;
            int hy = p / 18, hx = p - hy * 18;
            int iy = ty + hy - 1, ix = tx + hx - 1;
            bool in = ((unsigned)iy < 64u) & ((unsigned)ix < 64u);
            float v = in ? h1g[(cc * 4 + ch) * HW + iy * 64 + ix] : 0.0f;
            float sv = v / (1.0f + __expf(-v));
            float w0, w1, w2, w3; int k;
            spline_w(v, w0, w1, w2, w3, k);
            if (!in) k = -1000;                // padded input: all bases 0
            float bs[8];
#pragma unroll
            for (int idx = 0; idx < 8; ++idx) {
                int d = idx - k + 3;
                float r = (d == 0) ? w0 : 0.0f;
                r = (d == 1) ? w1 : r;
                r = (d == 2) ? w2 : r;
                r = (d == 3) ? w3 : r;
                bs[idx] = r;
            }
            int key = (p >> 1) & 3;
            uint4 pk;
            pk.x = bfpack(bs[0], bs[1]);
            pk.y = bfpack(bs[2], bs[3]);
            pk.z = bfpack(bs[4], bs[5]);
            pk.w = bfpack(bs[6], bs[7]);
            *reinterpret_cast<uint4*>(spl + p * 64 + ((ch ^ key) << 4)) = pk;
            int cg = cc * 4 + ch;              // global ch in group, 0..31
            *reinterpret_cast<unsigned short*>(
                slu + p * 64 + (((cg >> 3) ^ key) << 4) + ((cg * 2) & 15)) =
                (unsigned short)bf16r(sv);
        }
        __syncthreads();
        // spline MFMAs: K=32 = 4ch x 8basis; dy-reuse of each A-read
#pragma unroll
        for (int dx = 0; dx < 3; ++dx) {
            bf16x8 bf[3][2];
            const bf16x8* wp = wfs + (size_t)((((g * 8 + cc) * 3 + dx) * 3) * 2) * 64;
#pragma unroll
            for (int dy = 0; dy < 3; ++dy)
#pragma unroll
                for (int nf = 0; nf < 2; ++nf)
                    bf[dy][nf] = wp[(dy * 2 + nf) * 64 + lane];
#pragma unroll
            for (int hr = 0; hr < 6; ++hr) {
                int p = (hybase + hr) * 18 + lrow + dx;
                int ra = p * 64 + (((lhi ^ ((p >> 1) & 3))) << 4);
                bf16x8 af = *reinterpret_cast<const bf16x8*>(spl + ra);
#pragma unroll
                for (int dy = 0; dy < 3; ++dy) {
                    int y = hr - dy;
                    if (y >= 0 && y < 4) {
                        acc[y][0] = __builtin_amdgcn_mfma_f32_16x16x32_bf16(af, bf[dy][0], acc[y][0], 0, 0, 0);
                        acc[y][1] = __builtin_amdgcn_mfma_f32_16x16x32_bf16(af, bf[dy][1], acc[y][1], 0, 0, 0);
                    }
                }
            }
        }
    }
    // base branch: silu plane, K = 32 channels (k = lhi*8 + j)
#pragma unroll
    for (int dx = 0; dx < 3; ++dx) {
        bf16x8 bf[3][2];
        const bf16x8* wp = wfb + (size_t)(((g * 3 + dx) * 3) * 2) * 64;
#pragma unroll
        for (int dy = 0; dy < 3; ++dy)
#pragma unroll
            for (int nf = 0; nf < 2; ++nf)
                bf[dy][nf] = wp[(dy * 2 + nf) * 64 + lane];
#pragma unroll
        for (int hr = 0; hr < 6; ++hr) {
            int p = (hybase + hr) * 18 + lrow + dx;
            int ra = p * 64 + (((lhi ^ ((p >> 1) & 3))) << 4);
            bf16x8 af = *reinterpret_cast<const bf16x8*>(slu + ra);
#pragma unroll
            for (int dy = 0; dy < 3; ++dy) {
                int y = hr - dy;
                if (y >= 0 && y < 4) {
                    acc[y][0] = __builtin_amdgcn_mfma_f32_16x16x32_bf16(af, bf[dy][0], acc[y][0], 0, 0, 0);
                    acc[y][1] = __builtin_amdgcn_mfma_f32_16x16x32_bf16(af, bf[dy][1], acc[y][1], 0, 0, 0);
                }
            }
        }
    }
    // write: D row (m) = x = lhi*4 + reg, col (n) = co = lrow
#pragma unroll
    for (int y = 0; y < 4; ++y) {
        int oy = ty + w * 4 + y;
#pragma unroll
        for (int nf = 0; nf < 2; ++nf) {
            int co = g * 32 + nf * 16 + lrow;
            float4 o = {acc[y][nf][0], acc[y][nf][1], acc[y][nf][2], acc[y][nf][3]};
            *reinterpret_cast<float4*>(
                &h2[(((size_t)b * COUT + co) * 64 + oy) * 64 + tx + lhi * 4]) = o;
        }
    }
}

// ---- BN stats ----
__global__ void __launch_bounds__(256) bnstats_kernel(
    const float* __restrict__ h2, const float* __restrict__ gamma,
    const float* __restrict__ beta, float* __restrict__ stats) {
    int co = blockIdx.x;
    int tid = threadIdx.x;
    float s = 0.0f, ss = 0.0f;
    for (int b = 0; b < BATCH; ++b) {
        const float* p = h2 + (size_t)(b * COUT + co) * HW;
        for (int i = tid; i < HW; i += 256) {
            float v = p[i];
            s += v;
            ss = fmaf(v, v, ss);
        }
    }
    __shared__ float r1[256], r2[256];
    r1[tid] = s; r2[tid] = ss;
    __syncthreads();
    for (int o = 128; o > 0; o >>= 1) {
        if (tid < o) { r1[tid] += r1[tid + o]; r2[tid] += r2[tid + o]; }
        __syncthreads();
    }
    if (tid == 0) {
        const float invn = 1.0f / 65536.0f;
        float mean = r1[0] * invn;
        float var = r2[0] * invn - mean * mean;
        float sc = gamma[co] * rsqrtf(var + 1e-5f);
        stats[2 * co] = sc;
        stats[2 * co + 1] = beta[co] - mean * sc;
    }
}

// ---- BN apply ----
__global__ void __launch_bounds__(256) bnapply_kernel(
    const float* __restrict__ h2, const float* __restrict__ stats,
    float* __restrict__ out, int n4) {
    int i = blockIdx.x * 256 + threadIdx.x;
    if (i >= n4) return;
    int co = (i >> 10) & 255;
    float sc = stats[2 * co], sh = stats[2 * co + 1];
    float4 v = reinterpret_cast<const float4*>(h2)[i];
    float4 o;
    o.x = fmaf(v.x, sc, sh);
    o.y = fmaf(v.y, sc, sh);
    o.z = fmaf(v.z, sc, sh);
    o.w = fmaf(v.w, sc, sh);
    reinterpret_cast<float4*>(out)[i] = o;
}

extern "C" void kernel_launch(void* const* d_in, const int* in_sizes, int n_in,
                              void* d_out, int out_size, void* d_ws, size_t ws_size,
                              hipStream_t stream) {
    const float* x   = (const float*)d_in[0];
    const float* wb1 = (const float*)d_in[1];
    const float* bb1 = (const float*)d_in[2];
    const float* ws1 = (const float*)d_in[3];
    const float* wb2 = (const float*)d_in[4];
    const float* bb2 = (const float*)d_in[5];
    const float* ws2 = (const float*)d_in[6];
    const float* gamma = (const float*)d_in[7];
    const float* beta  = (const float*)d_in[8];

    const size_t HSZ = (size_t)BATCH * COUT * HW;   // 16,777,216 floats
    float* h1    = (float*)d_ws;
    float* h2    = h1 + HSZ;
    float* wp1   = h2 + HSZ;                         // 36,864 f32
    float* stats = wp1 + 36864;                      // 512 f32
    unsigned short* wfs = (unsigned short*)(stats + 512);   // 589,824 u16
    unsigned short* wfb = wfs + WFS_ELEMS;                  // 73,728 u16

    repack2_kernel<<<(WFS_ELEMS + 255) / 256, 256, 0, stream>>>(
        wb1, ws1, wb2, ws2, wp1, wfs, wfb);
    kan1_kernel<<<BATCH * GROUPS * 16, 256, 0, stream>>>(x, wp1, bb1, h1);
    kan2_mfma_kernel<<<BATCH * GROUPS * 16, 256, 0, stream>>>(
        h1, (const bf16x8*)wfs, (const bf16x8*)wfb, bb2, h2);
    bnstats_kernel<<<COUT, 256, 0, stream>>>(h2, gamma, beta, stats);
    bnapply_kernel<<<(4194304 + 255) / 256, 256, 0, stream>>>(
        h2, stats, (float*)d_out, 4194304);
}

// Round 5
// 281.426 us; speedup vs baseline: 4.2283x; 1.2082x over previous
//
#include <hip/hip_runtime.h>
#include <hip/hip_bf16.h>
#include <stdint.h>

// GSC_kan: two grouped KAN convs (1x1, 3x3; G=8) + BatchNorm.
// Round 5: kan2 was VALU-bound (55% VALU vs 21% Mfma). Move feature
// computation (silu + spline + bf16 pack) into kan1's epilogue, store
// pre-packed bf16 features in zero-padded 66x66 planes; kan2 staging
// becomes a pure global->reg->LDS copy overlapped with MFMA.
// Runtime ws_size guard falls back to the proven R4 path.

#define NB 8
#define NF 9
#define CIN 128
#define COUT 256
#define GROUPS 8
#define HW 4096
#define BATCH 16

#define WFS_ELEMS 589824   // 256 * 32 * 8 * 9
#define WFB_ELEMS 73728    // 256 * 32 * 9

#define PY 66
#define PCELLS (66 * 66)   // 4356

typedef __attribute__((ext_vector_type(8))) short bf16x8;
typedef __attribute__((ext_vector_type(4))) float f32x4;

__device__ __forceinline__ unsigned bf16r(float f) {
    union { float f; unsigned u; } c; c.f = f;
    unsigned r = c.u + 0x7FFF + ((c.u >> 16) & 1);   // RNE
    return r >> 16;
}
__device__ __forceinline__ unsigned bfpack(float lo, float hi) {
    return bf16r(lo) | (bf16r(hi) << 16);
}

// uniform-knot cubic B-spline: 4 nonzero cardinal weights at interval k.
__device__ __forceinline__ void spline_w(float v, float& w0, float& w1,
                                         float& w2, float& w3, int& k) {
    float s = (v + 2.2f) * 2.5f;
    float fk = floorf(s);
    k = (int)fk;
    float u = s - fk;
    float um = 1.0f - u;
    float u2 = u * u, u3 = u2 * u;
    w0 = um * um * um * (1.0f / 6.0f);
    w1 = (3.0f * u3 - 6.0f * u2 + 4.0f) * (1.0f / 6.0f);
    w2 = (-3.0f * u3 + 3.0f * u2 + 3.0f * u + 1.0f) * (1.0f / 6.0f);
    w3 = u3 * (1.0f / 6.0f);
}

__device__ __forceinline__ void spline_bases(float v, float* __restrict__ bs) {
    float w0, w1, w2, w3; int k;
    spline_w(v, w0, w1, w2, w3, k);
#pragma unroll
    for (int idx = 0; idx < 8; ++idx) {
        int d = idx - k + 3;
        float r = (d == 0) ? w0 : 0.0f;
        r = (d == 1) ? w1 : r;
        r = (d == 2) ? w2 : r;
        r = (d == 3) ? w3 : r;
        bs[idx] = r;
    }
}

__device__ __forceinline__ void kan_features_fast(float v, float* __restrict__ f) {
    f[0] = v / (1.0f + __expf(-v));
    spline_bases(v, f + 1);
}

// ---- repack: wp1 fp32 [g][c16][f9][co32]; wfs/wfb bf16 B-fragment layouts ----
__global__ void __launch_bounds__(256) repack2_kernel(
    const float* __restrict__ wb1, const float* __restrict__ ws1,
    const float* __restrict__ wb2, const float* __restrict__ ws2,
    float* __restrict__ wp1, unsigned short* __restrict__ wfs,
    unsigned short* __restrict__ wfb) {
    int i = blockIdx.x * 256 + threadIdx.x;
    if (i < 8 * 16 * 9 * 32) {
        int co = i & 31;
        int t = i >> 5;
        int f = t % 9; t /= 9;
        int c = t & 15; int g = t >> 4;
        int cog = g * 32 + co;
        wp1[i] = (f == 0) ? wb1[cog * 16 + c]
                          : ws1[cog * 128 + c * 8 + (f - 1)];
    }
    if (i < WFB_ELEMS) {
        int j = i & 7;
        int lane = (i >> 3) & 63;
        int nf = (i >> 9) & 1;
        int t = i >> 10;
        int dy = t % 3; t /= 3;
        int dx = t % 3; t /= 3;
        int g = t;
        int ch = (lane >> 4) * 8 + j;
        int cog = g * 32 + nf * 16 + (lane & 15);
        wfb[i] = (unsigned short)bf16r(wb2[((cog * 32 + ch) * 3 + dy) * 3 + dx]);
    }
    if (i < WFS_ELEMS) {
        int j = i & 7;
        int t = i >> 3;
        int lane = t & 63; t >>= 6;
        int nf = t & 1; t >>= 1;
        int dy = t % 3; t /= 3;
        int dx = t % 3; t /= 3;
        int cc = t & 7; t >>= 3;
        int g = t;
        int c_loc = cc * 4 + (lane >> 4);
        int cog = g * 32 + nf * 16 + (lane & 15);
        float v = ws2[((cog * 256 + c_loc * 8 + j) * 3 + dy) * 3 + dx];
        wfs[i] = (unsigned short)bf16r(v);
    }
}

// ---- zero the padded borders of sfeat (16B cells) and bfeat (64B cells) ----
__global__ void __launch_bounds__(256) border_kernel(
    uint4* __restrict__ sfe, uint4* __restrict__ bfe) {
    int i = blockIdx.x * 256 + threadIdx.x;
    if (i >= 4096 * 260) return;
    int plane = i / 260;
    int r = i - plane * 260;
    int yp, xp;
    if (r < 66)       { yp = 0;  xp = r; }
    else if (r < 132) { yp = 65; xp = r - 66; }
    else { int q = r - 132; yp = 1 + (q >> 1); xp = (q & 1) ? 65 : 0; }
    uint4 z = {0, 0, 0, 0};
    sfe[(size_t)plane * PCELLS + yp * PY + xp] = z;
    if (i < 128 * 260) {
        size_t c = ((size_t)plane * PCELLS + yp * PY + xp) * 4;
        bfe[c] = z; bfe[c + 1] = z; bfe[c + 2] = z; bfe[c + 3] = z;
    }
}

// ---- layer 1 fused: 1x1 grouped KAN conv + feature epilogue ----
// writes sfeat[bc][yp][xp] = 8 bf16 bases (16B), bfeat[bg][yp][xp][ch32] silu.
__global__ void __launch_bounds__(256) kan1f_kernel(
    const float* __restrict__ x, const float* __restrict__ wp1,
    const float* __restrict__ bb1, uint4* __restrict__ sfe,
    uint4* __restrict__ bfe) {
    int tid = threadIdx.x;
    int blk = blockIdx.x;
    int t = blk & 15;
    int g = (blk >> 4) & 7;
    int b = blk >> 7;
    int pos = t * 256 + tid;
    int y = pos >> 6, xx = pos & 63;

    float acc[32];
    const float* bb = bb1 + g * 32;
#pragma unroll
    for (int co = 0; co < 32; ++co) acc[co] = bb[co];

    for (int c = 0; c < 16; ++c) {
        float v = x[(b * CIN + g * 16 + c) * HW + pos];
        float ft[NF];
        kan_features_fast(v, ft);
        const float* wp = wp1 + ((g * 16 + c) * 9) * 32;
        for (int f = 0; f < NF; ++f) {
            float fv = ft[f];
#pragma unroll
            for (int co = 0; co < 32; ++co)
                acc[co] = fmaf(wp[f * 32 + co], fv, acc[co]);
        }
    }
    // feature epilogue
    size_t cell = (size_t)(y + 1) * PY + (xx + 1);
    size_t sbase = ((size_t)(b * 256 + g * 32)) * PCELLS + cell;
    unsigned su[16];
#pragma unroll
    for (int co = 0; co < 32; ++co) {
        float v = acc[co];
        float sv = v / (1.0f + __expf(-v));
        float bs[8];
        spline_bases(v, bs);
        uint4 pk;
        pk.x = bfpack(bs[0], bs[1]);
        pk.y = bfpack(bs[2], bs[3]);
        pk.z = bfpack(bs[4], bs[5]);
        pk.w = bfpack(bs[6], bs[7]);
        sfe[sbase + (size_t)co * PCELLS] = pk;
        unsigned h = bf16r(sv);
        if (co & 1) su[co >> 1] |= h << 16;
        else        su[co >> 1] = h;
    }
    size_t bbase = (((size_t)(b * 8 + g)) * PCELLS + cell) * 4;
#pragma unroll
    for (int q = 0; q < 4; ++q) {
        uint4 o = {su[q * 4], su[q * 4 + 1], su[q * 4 + 2], su[q * 4 + 3]};
        bfe[bbase + q] = o;
    }
}

// ---- layer 2: pure copy + MFMA. LDS [ch][324][16B], no swizzle needed. ----
__global__ void __launch_bounds__(256) kan2_ldg_kernel(
    const uint4* __restrict__ sfe, const uint4* __restrict__ bfe,
    const bf16x8* __restrict__ wfs, const bf16x8* __restrict__ wfb,
    const float* __restrict__ bb2, float* __restrict__ h2) {
    __shared__ __align__(16) unsigned char lds[41472];
    unsigned char* spl = lds;            // 20736 B: (ch*324 + p) * 16
    unsigned char* slu = lds + 20736;    // 20736 B: (cq*324 + p) * 16

    const int tid = threadIdx.x;
    const int lane = tid & 63;
    const int w = tid >> 6;
    const int blk = blockIdx.x;
    const int tile = blk & 15;
    const int g = (blk >> 4) & 7;
    const int b = blk >> 7;
    const int ty = (tile >> 2) * 16, tx = (tile & 3) * 16;
    const int lrow = lane & 15;
    const int lhi = lane >> 4;

    f32x4 acc[4][2];
#pragma unroll
    for (int y = 0; y < 4; ++y)
#pragma unroll
        for (int nf = 0; nf < 2; ++nf) {
            float bias = bb2[g * 32 + nf * 16 + lrow];
            acc[y][nf] = (f32x4){bias, bias, bias, bias};
        }

    const int hybase = w * 4;
    const size_t sfe_base = ((size_t)(b * 256 + g * 32)) * PCELLS;
    const size_t bfe_base = ((size_t)(b * 8 + g)) * PCELLS * 4;

    uint4 st[6];

    // ---- stage silu plane (once): e = p*4 + cq for coalesced 64B cells ----
#pragma unroll
    for (int it = 0; it < 6; ++it) {
        int e = tid + it * 256;
        if (e < 1296) {
            int p = e >> 2, cq = e & 3;
            int hy = p / 18, hx = p - hy * 18;
            st[it] = bfe[bfe_base + ((size_t)(ty + hy) * PY + (tx + hx)) * 4 + cq];
        }
    }
#pragma unroll
    for (int it = 0; it < 6; ++it) {
        int e = tid + it * 256;
        if (e < 1296) {
            int p = e >> 2, cq = e & 3;
            *reinterpret_cast<uint4*>(slu + (cq * 324 + p) * 16) = st[it];
        }
    }
    // ---- stage spline chunk 0 ----
#pragma unroll
    for (int it = 0; it < 6; ++it) {
        int e = tid + it * 256;
        if (e < 1296) {
            int ch = e / 324, p = e - ch * 324;
            int hy = p / 18, hx = p - hy * 18;
            st[it] = sfe[sfe_base + (size_t)ch * PCELLS +
                         (size_t)(ty + hy) * PY + (tx + hx)];
        }
    }
#pragma unroll
    for (int it = 0; it < 6; ++it) {
        int e = tid + it * 256;
        if (e < 1296)
            *reinterpret_cast<uint4*>(spl + e * 16) = st[it];
    }
    // ---- issue loads for chunk 1 (held in regs across MFMA of chunk 0) ----
#pragma unroll
    for (int it = 0; it < 6; ++it) {
        int e = tid + it * 256;
        if (e < 1296) {
            int ch = e / 324, p = e - ch * 324;
            int hy = p / 18, hx = p - hy * 18;
            st[it] = sfe[sfe_base + (size_t)(4 + ch) * PCELLS +
                         (size_t)(ty + hy) * PY + (tx + hx)];
        }
    }
    __syncthreads();

    for (int cc = 0; cc < 8; ++cc) {
        // MFMA phase on current chunk
#pragma unroll
        for (int dx = 0; dx < 3; ++dx) {
            bf16x8 bf[3][2];
            const bf16x8* wp = wfs + (size_t)((((g * 8 + cc) * 3 + dx) * 3) * 2) * 64;
#pragma unroll
            for (int dy = 0; dy < 3; ++dy)
#pragma unroll
                for (int nf = 0; nf < 2; ++nf)
                    bf[dy][nf] = wp[(dy * 2 + nf) * 64 + lane];
#pragma unroll
            for (int hr = 0; hr < 6; ++hr) {
                int p = (hybase + hr) * 18 + lrow + dx;
                bf16x8 af = *reinterpret_cast<const bf16x8*>(spl + (lhi * 324 + p) * 16);
#pragma unroll
                for (int dy = 0; dy < 3; ++dy) {
                    int y = hr - dy;
                    if (y >= 0 && y < 4) {
                        acc[y][0] = __builtin_amdgcn_mfma_f32_16x16x32_bf16(af, bf[dy][0], acc[y][0], 0, 0, 0);
                        acc[y][1] = __builtin_amdgcn_mfma_f32_16x16x32_bf16(af, bf[dy][1], acc[y][1], 0, 0, 0);
                    }
                }
            }
        }
        __syncthreads();   // all waves done reading this chunk
        if (cc < 7) {
            // write next chunk (regs already loaded), issue loads for cc+2
#pragma unroll
            for (int it = 0; it < 6; ++it) {
                int e = tid + it * 256;
                if (e < 1296)
                    *reinterpret_cast<uint4*>(spl + e * 16) = st[it];
            }
            if (cc < 6) {
#pragma unroll
                for (int it = 0; it < 6; ++it) {
                    int e = tid + it * 256;
                    if (e < 1296) {
                        int ch = e / 324, p = e - ch * 324;
                        int hy = p / 18, hx = p - hy * 18;
                        st[it] = sfe[sfe_base + (size_t)((cc + 2) * 4 + ch) * PCELLS +
                                     (size_t)(ty + hy) * PY + (tx + hx)];
                    }
                }
            }
            __syncthreads();
        }
    }
    // base branch from slu (staged at start)
#pragma unroll
    for (int dx = 0; dx < 3; ++dx) {
        bf16x8 bf[3][2];
        const bf16x8* wp = wfb + (size_t)(((g * 3 + dx) * 3) * 2) * 64;
#pragma unroll
        for (int dy = 0; dy < 3; ++dy)
#pragma unroll
            for (int nf = 0; nf < 2; ++nf)
                bf[dy][nf] = wp[(dy * 2 + nf) * 64 + lane];
#pragma unroll
        for (int hr = 0; hr < 6; ++hr) {
            int p = (hybase + hr) * 18 + lrow + dx;
            bf16x8 af = *reinterpret_cast<const bf16x8*>(slu + (lhi * 324 + p) * 16);
#pragma unroll
            for (int dy = 0; dy < 3; ++dy) {
                int y = hr - dy;
                if (y >= 0 && y < 4) {
                    acc[y][0] = __builtin_amdgcn_mfma_f32_16x16x32_bf16(af, bf[dy][0], acc[y][0], 0, 0, 0);
                    acc[y][1] = __builtin_amdgcn_mfma_f32_16x16x32_bf16(af, bf[dy][1], acc[y][1], 0, 0, 0);
                }
            }
        }
    }
#pragma unroll
    for (int y = 0; y < 4; ++y) {
        int oy = ty + w * 4 + y;
#pragma unroll
        for (int nf = 0; nf < 2; ++nf) {
            int co = g * 32 + nf * 16 + lrow;
            float4 o = {acc[y][nf][0], acc[y][nf][1], acc[y][nf][2], acc[y][nf][3]};
            *reinterpret_cast<float4*>(
                &h2[(((size_t)b * COUT + co) * 64 + oy) * 64 + tx + lhi * 4]) = o;
        }
    }
}

// ==================== fallback (proven R4) kernels ====================
__global__ void __launch_bounds__(256) kan1_kernel(
    const float* __restrict__ x, const float* __restrict__ wp1,
    const float* __restrict__ bb1, float* __restrict__ h1) {
    int tid = threadIdx.x;
    int blk = blockIdx.x;
    int t = blk & 15;
    int g = (blk >> 4) & 7;
    int b = blk >> 7;
    int pos = t * 256 + tid;

    float acc[32];
    const float* bb = bb1 + g * 32;
#pragma unroll
    for (int co = 0; co < 32; ++co) acc[co] = bb[co];

    for (int c = 0; c < 16; ++c) {
        float v = x[(b * CIN + g * 16 + c) * HW + pos];
        float ft[NF];
        kan_features_fast(v, ft);
        const float* wp = wp1 + ((g * 16 + c) * 9) * 32;
        for (int f = 0; f < NF; ++f) {
            float fv = ft[f];
#pragma unroll
            for (int co = 0; co < 32; ++co)
                acc[co] = fmaf(wp[f * 32 + co], fv, acc[co]);
        }
    }
    float* op = h1 + (b * COUT + g * 32) * HW + pos;
#pragma unroll
    for (int co = 0; co < 32; ++co) op[co * HW] = acc[co];
}

__global__ void __launch_bounds__(256) kan2_mfma_kernel(
    const float* __restrict__ h1, const bf16x8* __restrict__ wfs,
    const bf16x8* __restrict__ wfb, const float* __restrict__ bb2,
    float* __restrict__ h2) {
    __shared__ __align__(16) unsigned char lds[41472];
    unsigned char* spl = lds;
    unsigned char* slu = lds + 20736;

    const int tid = threadIdx.x;
    const int lane = tid & 63;
    const int w = tid >> 6;
    const int blk = blockIdx.x;
    const int tile = blk & 15;
    const int g = (blk >> 4) & 7;
    const int b = blk >> 7;
    const int ty = (tile >> 2) * 16, tx = (tile & 3) * 16;
    const int lrow = lane & 15;
    const int lhi = lane >> 4;

    f32x4 acc[4][2];
#pragma unroll
    for (int y = 0; y < 4; ++y)
#pragma unroll
        for (int nf = 0; nf < 2; ++nf) {
            float bias = bb2[g * 32 + nf * 16 + lrow];
            acc[y][nf] = (f32x4){bias, bias, bias, bias};
        }

    const float* h1g = h1 + (size_t)(b * COUT + g * 32) * HW;
    const int hybase = w * 4;

    for (int cc = 0; cc < 8; ++cc) {
        __syncthreads();
        for (int e = tid; e < 1296; e += 256) {
            int ch = e / 324;
            int p = e - ch * 324;
            int hy = p / 18, hx = p - hy * 18;
            int iy = ty + hy - 1, ix = tx + hx - 1;
            bool in = ((unsigned)iy < 64u) & ((unsigned)ix < 64u);
            float v = in ? h1g[(cc * 4 + ch) * HW + iy * 64 + ix] : 0.0f;
            float sv = v / (1.0f + __expf(-v));
            float w0, w1, w2, w3; int k;
            spline_w(v, w0, w1, w2, w3, k);
            if (!in) k = -1000;
            float bs[8];
#pragma unroll
            for (int idx = 0; idx < 8; ++idx) {
                int d = idx - k + 3;
                float r = (d == 0) ? w0 : 0.0f;
                r = (d == 1) ? w1 : r;
                r = (d == 2) ? w2 : r;
                r = (d == 3) ? w3 : r;
                bs[idx] = r;
            }
            int key = (p >> 1) & 3;
            uint4 pk;
            pk.x = bfpack(bs[0], bs[1]);
            pk.y = bfpack(bs[2], bs[3]);
            pk.z = bfpack(bs[4], bs[5]);
            pk.w = bfpack(bs[6], bs[7]);
            *reinterpret_cast<uint4*>(spl + p * 64 + ((ch ^ key) << 4)) = pk;
            int cg = cc * 4 + ch;
            *reinterpret_cast<unsigned short*>(
                slu + p * 64 + (((cg >> 3) ^ key) << 4) + ((cg * 2) & 15)) =
                (unsigned short)bf16r(sv);
        }
        __syncthreads();
#pragma unroll
        for (int dx = 0; dx < 3; ++dx) {
            bf16x8 bf[3][2];
            const bf16x8* wp = wfs + (size_t)((((g * 8 + cc) * 3 + dx) * 3) * 2) * 64;
#pragma unroll
            for (int dy = 0; dy < 3; ++dy)
#pragma unroll
                for (int nf = 0; nf < 2; ++nf)
                    bf[dy][nf] = wp[(dy * 2 + nf) * 64 + lane];
#pragma unroll
            for (int hr = 0; hr < 6; ++hr) {
                int p = (hybase + hr) * 18 + lrow + dx;
                int ra = p * 64 + (((lhi ^ ((p >> 1) & 3))) << 4);
                bf16x8 af = *reinterpret_cast<const bf16x8*>(spl + ra);
#pragma unroll
                for (int dy = 0; dy < 3; ++dy) {
                    int y = hr - dy;
                    if (y >= 0 && y < 4) {
                        acc[y][0] = __builtin_amdgcn_mfma_f32_16x16x32_bf16(af, bf[dy][0], acc[y][0], 0, 0, 0);
                        acc[y][1] = __builtin_amdgcn_mfma_f32_16x16x32_bf16(af, bf[dy][1], acc[y][1], 0, 0, 0);
                    }
                }
            }
        }
    }
#pragma unroll
    for (int dx = 0; dx < 3; ++dx) {
        bf16x8 bf[3][2];
        const bf16x8* wp = wfb + (size_t)(((g * 3 + dx) * 3) * 2) * 64;
#pragma unroll
        for (int dy = 0; dy < 3; ++dy)
#pragma unroll
            for (int nf = 0; nf < 2; ++nf)
                bf[dy][nf] = wp[(dy * 2 + nf) * 64 + lane];
#pragma unroll
        for (int hr = 0; hr < 6; ++hr) {
            int p = (hybase + hr) * 18 + lrow + dx;
            int ra = p * 64 + (((lhi ^ ((p >> 1) & 3))) << 4);
            bf16x8 af = *reinterpret_cast<const bf16x8*>(slu + ra);
#pragma unroll
            for (int dy = 0; dy < 3; ++dy) {
                int y = hr - dy;
                if (y >= 0 && y < 4) {
                    acc[y][0] = __builtin_amdgcn_mfma_f32_16x16x32_bf16(af, bf[dy][0], acc[y][0], 0, 0, 0);
                    acc[y][1] = __builtin_amdgcn_mfma_f32_16x16x32_bf16(af, bf[dy][1], acc[y][1], 0, 0, 0);
                }
            }
        }
    }
#pragma unroll
    for (int y = 0; y < 4; ++y) {
        int oy = ty + w * 4 + y;
#pragma unroll
        for (int nf = 0; nf < 2; ++nf) {
            int co = g * 32 + nf * 16 + lrow;
            float4 o = {acc[y][nf][0], acc[y][nf][1], acc[y][nf][2], acc[y][nf][3]};
            *reinterpret_cast<float4*>(
                &h2[(((size_t)b * COUT + co) * 64 + oy) * 64 + tx + lhi * 4]) = o;
        }
    }
}

// ---- BN stage 1: per-(b,co) plane partial sums ----
__global__ void __launch_bounds__(256) bnp1_kernel(
    const float* __restrict__ h2, float* __restrict__ partial) {
    int bc = blockIdx.x;
    int tid = threadIdx.x;
    const float4* p = reinterpret_cast<const float4*>(h2 + (size_t)bc * HW);
    float s = 0.0f, ss = 0.0f;
#pragma unroll
    for (int it = 0; it < 4; ++it) {
        float4 v = p[tid + it * 256];
        s += v.x + v.y + v.z + v.w;
        ss = fmaf(v.x, v.x, ss); ss = fmaf(v.y, v.y, ss);
        ss = fmaf(v.z, v.z, ss); ss = fmaf(v.w, v.w, ss);
    }
    __shared__ float r1[256], r2[256];
    r1[tid] = s; r2[tid] = ss;
    __syncthreads();
    for (int o = 128; o > 0; o >>= 1) {
        if (tid < o) { r1[tid] += r1[tid + o]; r2[tid] += r2[tid + o]; }
        __syncthreads();
    }
    if (tid == 0) { partial[2 * bc] = r1[0]; partial[2 * bc + 1] = r2[0]; }
}

// ---- BN stage 2: reduce over batch, write scale/shift ----
__global__ void __launch_bounds__(256) bnp2_kernel(
    const float* __restrict__ partial, const float* __restrict__ gamma,
    const float* __restrict__ beta, float* __restrict__ stats) {
    int co = threadIdx.x;
    float s = 0.0f, ss = 0.0f;
    for (int b = 0; b < BATCH; ++b) {
        s += partial[2 * (b * 256 + co)];
        ss += partial[2 * (b * 256 + co) + 1];
    }
    const float invn = 1.0f / 65536.0f;
    float mean = s * invn;
    float var = ss * invn - mean * mean;
    float sc = gamma[co] * rsqrtf(var + 1e-5f);
    stats[2 * co] = sc;
    stats[2 * co + 1] = beta[co] - mean * sc;
}

// ---- BN apply (in place on d_out) ----
__global__ void __launch_bounds__(256) bnapply_kernel(
    float* __restrict__ h2, const float* __restrict__ stats, int n4) {
    int i = blockIdx.x * 256 + threadIdx.x;
    if (i >= n4) return;
    int co = (i >> 10) & 255;
    float sc = stats[2 * co], sh = stats[2 * co + 1];
    float4 v = reinterpret_cast<float4*>(h2)[i];
    float4 o;
    o.x = fmaf(v.x, sc, sh);
    o.y = fmaf(v.y, sc, sh);
    o.z = fmaf(v.z, sc, sh);
    o.w = fmaf(v.w, sc, sh);
    reinterpret_cast<float4*>(h2)[i] = o;
}

extern "C" void kernel_launch(void* const* d_in, const int* in_sizes, int n_in,
                              void* d_out, int out_size, void* d_ws, size_t ws_size,
                              hipStream_t stream) {
    const float* x   = (const float*)d_in[0];
    const float* wb1 = (const float*)d_in[1];
    const float* bb1 = (const float*)d_in[2];
    const float* ws1 = (const float*)d_in[3];
    const float* wb2 = (const float*)d_in[4];
    const float* bb2 = (const float*)d_in[5];
    const float* ws2 = (const float*)d_in[6];
    const float* gamma = (const float*)d_in[7];
    const float* beta  = (const float*)d_in[8];

    char* ws = (char*)d_ws;
    float* wp1   = (float*)ws;                                    // 147,456 B
    unsigned short* wfs = (unsigned short*)(ws + 147456);         // 1,179,648 B
    unsigned short* wfb = (unsigned short*)(ws + 1327104);        // 147,456 B
    float* partial = (float*)(ws + 1474560);                      // 32,768 B
    float* stats   = (float*)(ws + 1507328);                      // 2,048 B
    const size_t BASE = 1509376;

    float* h2 = (float*)d_out;   // conv2 output lives in d_out; BN is in-place

    const size_t SFE_BYTES = (size_t)BATCH * COUT * PCELLS * 16;  // 285,474,816
    const size_t BFE_BYTES = (size_t)BATCH * GROUPS * PCELLS * 64; // 35,684,352
    const size_t NEED_A = BASE + SFE_BYTES + BFE_BYTES;           // ~322.7 MB

    repack2_kernel<<<(WFS_ELEMS + 255) / 256, 256, 0, stream>>>(
        wb1, ws1, wb2, ws2, wp1, wfs, wfb);

    if (ws_size >= NEED_A) {
        uint4* sfe = (uint4*)(ws + BASE);
        uint4* bfe = (uint4*)(ws + BASE + SFE_BYTES);
        border_kernel<<<(4096 * 260 + 255) / 256, 256, 0, stream>>>(sfe, bfe);
        kan1f_kernel<<<BATCH * GROUPS * 16, 256, 0, stream>>>(
            x, wp1, bb1, sfe, bfe);
        kan2_ldg_kernel<<<BATCH * GROUPS * 16, 256, 0, stream>>>(
            sfe, bfe, (const bf16x8*)wfs, (const bf16x8*)wfb, bb2, h2);
    } else {
        float* h1 = (float*)(ws + BASE);
        kan1_kernel<<<BATCH * GROUPS * 16, 256, 0, stream>>>(x, wp1, bb1, h1);
        kan2_mfma_kernel<<<BATCH * GROUPS * 16, 256, 0, stream>>>(
            h1, (const bf16x8*)wfs, (const bf16x8*)wfb, bb2, h2);
    }

    bnp1_kernel<<<BATCH * COUT, 256, 0, stream>>>(h2, partial);
    bnp2_kernel<<<1, 256, 0, stream>>>(partial, gamma, beta, stats);
    bnapply_kernel<<<(4194304 + 255) / 256, 256, 0, stream>>>(
        h2, stats, 4194304);
}